// Round 2
// baseline (3880.750 us; speedup 1.0000x reference)
//
#include <hip/hip_runtime.h>

#define TLEN 512
#define FIN 16

__device__ __forceinline__ float sigm(float x) { return 1.0f / (1.0f + __expf(-x)); }
__device__ __forceinline__ float tanh_f(float x) {
  x = fminf(fmaxf(x, -15.0f), 15.0f);
  float e = __expf(2.0f * x);
  return (e - 1.0f) / (e + 1.0f);
}

// Symmetric pair-finish for GRU: lanes (2g,2g+1) hold (z,r) gate sums; both
// compute the identical update via shfl_xor (no divergence, no barrier).
__device__ __forceinline__ float gru_fin(float own_main, float own_xh, float own_hhp,
                                         int role, float hold) {
  const float oth_main = __shfl_xor(own_main, 1);
  const float xh  = own_xh  + __shfl_xor(own_xh, 1);
  const float hhp = own_hhp + __shfl_xor(own_hhp, 1);
  const float sz = role ? oth_main : own_main;
  const float sr = role ? own_main : oth_main;
  const float z = sigm(sz);
  const float r = sigm(sr);
  const float hh = tanh_f(xh + r * hhp);
  return z * hold + (1.f - z) * hh;
}

// Layer-pipelined GRU stack: 1 batch per block, 4 waves.
//   w0: L0 units 0-31 (t=i)   + L3 A-partials (k3 . h2, t=i-3)
//   w1: L0 units 32-63 (t=i)  + input prefetch (t=i+2)
//   w2: L1 (t=i-1)
//   w3: L2 (t=i-2)            + L3 B-part + combine/update (t=i-4)
// One __syncthreads per interval. All weights in registers, LDS reads are
// broadcasts. Double-buffered h-state, all producer->consumer gaps = 1.
__global__ __launch_bounds__(256, 2)
void rnn_pipe(const float* __restrict__ x, const float* __restrict__ emb,
              const float* __restrict__ k0, const float* __restrict__ r0,
              const float* __restrict__ bi0, const float* __restrict__ bh0,
              const float* __restrict__ k1, const float* __restrict__ r1,
              const float* __restrict__ bi1, const float* __restrict__ bh1,
              const float* __restrict__ k2, const float* __restrict__ r2,
              const float* __restrict__ bi2, const float* __restrict__ bh2,
              const float* __restrict__ k3, const float* __restrict__ r3,
              const float* __restrict__ bi3, const float* __restrict__ bh3,
              const float* __restrict__ w1, const float* __restrict__ b1,
              const float* __restrict__ w2, const float* __restrict__ b2,
              const float* __restrict__ vv, const float* __restrict__ bv,
              const float* __restrict__ wd, const float* __restrict__ bd,
              float* __restrict__ out, float* __restrict__ obuf)
{
  __shared__ __align__(16) float s_h0[2][64];
  __shared__ __align__(16) float s_h1[2][32];
  __shared__ __align__(16) float s_h2[2][32];
  __shared__ __align__(16) float s_h3[2][32];
  __shared__ __align__(16) float s_inp[2][20];
  __shared__ __align__(16) float s_emb[TLEN][4];
  __shared__ __align__(16) float s_pA[2][64];
  __shared__ __align__(16) float s_pAh[2][64];
  // epilogue buffers
  __shared__ __align__(16) float e_w1[1024];
  __shared__ __align__(16) float e_sc[TLEN];
  __shared__ float e_hw2[32], e_b1[32], e_v[32], e_part[256], e_ctx[32];

  const int tid  = threadIdx.x;
  const int wid  = tid >> 6;
  const int lane = tid & 63;
  const int g    = lane >> 1;
  const int role = lane & 1;
  const int b    = blockIdx.x;

  float Wa[96], Wb[48], Wc[48];
  float bm = 0.f, bxh = 0.f, bhh = 0.f;
  float cbm = 0.f, cbxh = 0.f, cbhh = 0.f;
  float rxP = 0.f;

  // ---------------- weight loading (registers) ----------------
  if (wid <= 1) {                       // L0: unit u, gate-col cm
    const int u  = wid * 32 + g;
    const int cm = role ? 64 + u : u;
    #pragma unroll
    for (int j = 0; j < 19; ++j) Wa[j] = k0[j*192 + cm];
    Wa[19] = 0.f;
    #pragma unroll
    for (int j = 0; j < 64; ++j) Wa[20+j] = r0[j*192 + cm];
    #pragma unroll
    for (int jj = 0; jj < 10; ++jj) {
      const int row = role*10 + jj;
      Wb[jj] = (row < 19) ? k0[row*192 + 128 + u] : 0.f;
    }
    #pragma unroll
    for (int jj = 0; jj < 32; ++jj) Wb[10+jj] = r0[(role*32+jj)*192 + 128 + u];
    bm  = bi0[cm] + bh0[cm];
    bxh = role ? 0.f : bi0[128+u];
    bhh = role ? bh0[128+u] : 0.f;
  }
  if (wid == 0) {                       // L3 A-part: k3 over h2
    const int cma = role ? 32 + g : g;
    #pragma unroll
    for (int j = 0; j < 32; ++j) Wc[j] = k3[j*96 + cma];
    #pragma unroll
    for (int jj = 0; jj < 16; ++jj) Wc[32+jj] = k3[(role*16+jj)*96 + 64 + g];
  }
  if (wid == 2) {                       // L1
    const int cm = role ? 32 + g : g;
    #pragma unroll
    for (int j = 0; j < 64; ++j) Wa[j] = k1[j*96 + cm];
    #pragma unroll
    for (int j = 0; j < 32; ++j) Wa[64+j] = r1[j*96 + cm];
    #pragma unroll
    for (int jj = 0; jj < 32; ++jj) Wb[jj] = k1[(role*32+jj)*96 + 64 + g];
    #pragma unroll
    for (int jj = 0; jj < 16; ++jj) Wb[32+jj] = r1[(role*16+jj)*96 + 64 + g];
    bm  = bi1[cm] + bh1[cm];
    bxh = role ? 0.f : bi1[64+g];
    bhh = role ? bh1[64+g] : 0.f;
  }
  if (wid == 3) {                       // L2 + L3 B-part/combine
    const int cm = role ? 32 + g : g;
    #pragma unroll
    for (int j = 0; j < 32; ++j) Wa[j] = k2[j*96 + cm];
    #pragma unroll
    for (int j = 0; j < 32; ++j) Wa[32+j] = r2[j*96 + cm];
    #pragma unroll
    for (int jj = 0; jj < 16; ++jj) Wb[jj] = k2[(role*16+jj)*96 + 64 + g];
    #pragma unroll
    for (int jj = 0; jj < 16; ++jj) Wb[16+jj] = r2[(role*16+jj)*96 + 64 + g];
    bm  = bi2[cm] + bh2[cm];
    bxh = role ? 0.f : bi2[64+g];
    bhh = role ? bh2[64+g] : 0.f;
    #pragma unroll
    for (int j = 0; j < 32; ++j) Wc[j] = r3[j*96 + cm];
    #pragma unroll
    for (int jj = 0; jj < 16; ++jj) Wc[32+jj] = r3[(role*16+jj)*96 + 64 + g];
    cbm  = bi3[cm] + bh3[cm];
    cbxh = bi3[64+g];
    cbhh = bh3[64+g];
  }

  // ---------------- state init + embedding pre-gather ----------------
  if (tid < 64)       { s_h0[0][tid] = 0.f; s_h0[1][tid] = 0.f; }
  else if (tid < 96)  { const int q = tid-64;  s_h1[0][q]=0.f; s_h1[1][q]=0.f; }
  else if (tid < 128) { const int q = tid-96;  s_h2[0][q]=0.f; s_h2[1][q]=0.f; }
  else if (tid < 160) { const int q = tid-128; s_h3[0][q]=0.f; s_h3[1][q]=0.f; }
  else if (tid < 180) { const int q = tid-160; s_inp[0][q]=0.f; s_inp[1][q]=0.f; }

  for (int t2 = tid; t2 < TLEN; t2 += 256) {
    const int id = (int)x[((size_t)b*TLEN + t2)*FIN + 1];
    const float4 e4 = *(const float4*)&emb[id*4];
    *(float4*)&s_emb[t2][0] = e4;
  }
  if (wid == 1 && lane < 16) rxP = x[((size_t)b*TLEN + 1)*FIN + lane];
  __syncthreads();
  if (tid < 16) {                       // stage t=0 into slot 0
    const float v = x[((size_t)b*TLEN + 0)*FIN + tid];
    if (tid == 0) s_inp[0][0] = v;
    else if (tid >= 2) s_inp[0][tid-1] = v;
    if (tid < 4) s_inp[0][15+tid] = s_emb[0][tid];
  }

  // ---------------- pipelined recurrence ----------------
  for (int i = 0; i < 516; ++i) {
    __syncthreads();
    const int wp = i & 1;
    const int rp = wp ^ 1;

    if (wid <= 1) {
      if (i < 512) {                                    // ---- L0, t=i
        const int u = wid*32 + g;
        float a0 = bm, a1 = 0.f, a2 = 0.f, a3 = 0.f;
        #pragma unroll
        for (int j = 0; j < 20; j += 4) {
          const float4 q = *(const float4*)&s_inp[wp][j];
          a0 += Wa[j]*q.x; a1 += Wa[j+1]*q.y; a2 += Wa[j+2]*q.z; a3 += Wa[j+3]*q.w;
        }
        #pragma unroll
        for (int j = 0; j < 64; j += 4) {
          const float4 q = *(const float4*)&s_h0[rp][j];
          a0 += Wa[20+j]*q.x; a1 += Wa[21+j]*q.y; a2 += Wa[22+j]*q.z; a3 += Wa[23+j]*q.w;
        }
        float xq = bxh;
        #pragma unroll
        for (int jj = 0; jj < 10; ++jj) xq += Wb[jj]*s_inp[wp][role*10+jj];
        float p0 = bhh, p1 = 0.f;
        #pragma unroll
        for (int jj = 0; jj < 32; jj += 4) {
          const float4 q = *(const float4*)&s_h0[rp][role*32+jj];
          p0 += Wb[10+jj]*q.x + Wb[12+jj]*q.z;
          p1 += Wb[11+jj]*q.y + Wb[13+jj]*q.w;
        }
        const float hold = s_h0[rp][u];
        const float hn = gru_fin(a0+a1+a2+a3, xq, p0+p1, role, hold);
        if (!role) s_h0[wp][u] = hn;
      }
      if (wid == 0) {
        if (i >= 3 && i <= 514) {                       // ---- L3 A-part, t=i-3
          float q0=0.f,q1=0.f,q2=0.f,q3=0.f;
          #pragma unroll
          for (int j = 0; j < 32; j += 4) {
            const float4 q = *(const float4*)&s_h2[rp][j];
            q0 += Wc[j]*q.x; q1 += Wc[j+1]*q.y; q2 += Wc[j+2]*q.z; q3 += Wc[j+3]*q.w;
          }
          float ph0=0.f, ph1=0.f;
          #pragma unroll
          for (int jj = 0; jj < 16; jj += 4) {
            const float4 q = *(const float4*)&s_h2[rp][role*16+jj];
            ph0 += Wc[32+jj]*q.x + Wc[34+jj]*q.z;
            ph1 += Wc[33+jj]*q.y + Wc[35+jj]*q.w;
          }
          s_pA[wp][lane]  = q0+q1+q2+q3;
          s_pAh[wp][lane] = ph0+ph1;
        }
      } else {                                          // ---- w1: prefetch
        if (lane < 16) {
          if (i + 1 <= 511) {
            const int slot = (i+1)&1;
            const float v = rxP;
            if (lane == 0) s_inp[slot][0] = v;
            else if (lane >= 2) s_inp[slot][lane-1] = v;
            if (lane < 4) s_inp[slot][15+lane] = s_emb[i+1][lane];
          }
          if (i + 2 <= 511) rxP = x[((size_t)b*TLEN + (i+2))*FIN + lane];
        }
      }
    } else if (wid == 2) {
      if (i >= 1 && i <= 512) {                         // ---- L1, t=i-1
        float a0 = bm, a1=0.f, a2=0.f, a3=0.f;
        #pragma unroll
        for (int j = 0; j < 64; j += 4) {
          const float4 q = *(const float4*)&s_h0[rp][j];
          a0 += Wa[j]*q.x; a1 += Wa[j+1]*q.y; a2 += Wa[j+2]*q.z; a3 += Wa[j+3]*q.w;
        }
        #pragma unroll
        for (int j = 0; j < 32; j += 4) {
          const float4 q = *(const float4*)&s_h1[rp][j];
          a0 += Wa[64+j]*q.x; a1 += Wa[65+j]*q.y; a2 += Wa[66+j]*q.z; a3 += Wa[67+j]*q.w;
        }
        float x0 = bxh, x1 = 0.f;
        #pragma unroll
        for (int jj = 0; jj < 32; jj += 4) {
          const float4 q = *(const float4*)&s_h0[rp][role*32+jj];
          x0 += Wb[jj]*q.x + Wb[jj+2]*q.z;
          x1 += Wb[jj+1]*q.y + Wb[jj+3]*q.w;
        }
        float p0 = bhh, p1 = 0.f;
        #pragma unroll
        for (int jj = 0; jj < 16; jj += 4) {
          const float4 q = *(const float4*)&s_h1[rp][role*16+jj];
          p0 += Wb[32+jj]*q.x + Wb[34+jj]*q.z;
          p1 += Wb[33+jj]*q.y + Wb[35+jj]*q.w;
        }
        const float hold = s_h1[rp][g];
        const float hn = gru_fin(a0+a1+a2+a3, x0+x1, p0+p1, role, hold);
        if (!role) s_h1[wp][g] = hn;
      }
    } else {
      if (i >= 2 && i <= 513) {                         // ---- L2, t=i-2
        float a0 = bm, a1=0.f, a2=0.f, a3=0.f;
        #pragma unroll
        for (int j = 0; j < 32; j += 4) {
          const float4 q = *(const float4*)&s_h1[rp][j];
          a0 += Wa[j]*q.x; a1 += Wa[j+1]*q.y; a2 += Wa[j+2]*q.z; a3 += Wa[j+3]*q.w;
        }
        #pragma unroll
        for (int j = 0; j < 32; j += 4) {
          const float4 q = *(const float4*)&s_h2[rp][j];
          a0 += Wa[32+j]*q.x; a1 += Wa[33+j]*q.y; a2 += Wa[34+j]*q.z; a3 += Wa[35+j]*q.w;
        }
        float x0 = bxh, x1 = 0.f;
        #pragma unroll
        for (int jj = 0; jj < 16; jj += 4) {
          const float4 q = *(const float4*)&s_h1[rp][role*16+jj];
          x0 += Wb[jj]*q.x + Wb[jj+2]*q.z;
          x1 += Wb[jj+1]*q.y + Wb[jj+3]*q.w;
        }
        float p0 = bhh, p1 = 0.f;
        #pragma unroll
        for (int jj = 0; jj < 16; jj += 4) {
          const float4 q = *(const float4*)&s_h2[rp][role*16+jj];
          p0 += Wb[16+jj]*q.x + Wb[18+jj]*q.z;
          p1 += Wb[17+jj]*q.y + Wb[19+jj]*q.w;
        }
        const float hold = s_h2[rp][g];
        const float hn = gru_fin(a0+a1+a2+a3, x0+x1, p0+p1, role, hold);
        if (!role) s_h2[wp][g] = hn;
      }
      if (i >= 4) {                                     // ---- L3 B + combine, t=i-4
        float q0=0.f,q1=0.f,q2=0.f,q3=0.f;
        #pragma unroll
        for (int j = 0; j < 32; j += 4) {
          const float4 q = *(const float4*)&s_h3[rp][j];
          q0 += Wc[j]*q.x; q1 += Wc[j+1]*q.y; q2 += Wc[j+2]*q.z; q3 += Wc[j+3]*q.w;
        }
        float ph0=0.f, ph1=0.f;
        #pragma unroll
        for (int jj = 0; jj < 16; jj += 4) {
          const float4 q = *(const float4*)&s_h3[rp][role*16+jj];
          ph0 += Wc[32+jj]*q.x + Wc[34+jj]*q.z;
          ph1 += Wc[33+jj]*q.y + Wc[35+jj]*q.w;
        }
        const float own_main = s_pA[rp][lane] + (q0+q1+q2+q3) + cbm;
        const float ownxh = s_pAh[rp][lane];
        const float ownph = ph0 + ph1;
        const float oth_main = __shfl_xor(own_main, 1);
        const float xh  = ownxh + __shfl_xor(ownxh, 1) + cbxh;
        const float hhp = ownph + __shfl_xor(ownph, 1) + cbhh;
        const float sz = role ? oth_main : own_main;
        const float sr = role ? own_main : oth_main;
        const float z = sigm(sz);
        const float r = sigm(sr);
        const float hh = tanh_f(xh + r*hhp);
        const float hold = s_h3[rp][g];
        const float hn = z*hold + (1.f-z)*hh;
        if (!role) {
          s_h3[wp][g] = hn;
          obuf[((size_t)b*TLEN + (i-4))*32 + g] = hn;
        }
      }
    }
  }
  __syncthreads();

  // ---------------- attention epilogue (hT = s_h3[1]) ----------------
  for (int kk = tid; kk < 1024; kk += 256) e_w1[kk] = w1[kk];
  if (tid < 32) { e_b1[tid] = b1[tid]; e_v[tid] = vv[tid]; }
  if (tid >= 64 && tid < 96) {
    const int u = tid - 64;
    float s = b2[u];
    #pragma unroll
    for (int j = 0; j < 32; ++j) s += s_h3[1][j] * w2[j*32 + u];
    e_hw2[u] = s;
  }
  __syncthreads();

  #pragma unroll
  for (int c = 0; c < 2; ++c) {
    const int t2 = c*256 + tid;
    const float* row = obuf + ((size_t)b*TLEN + t2)*32;
    float rr[32];
    #pragma unroll
    for (int j = 0; j < 32; j += 4) {
      const float4 r4 = *(const float4*)&row[j];
      rr[j]=r4.x; rr[j+1]=r4.y; rr[j+2]=r4.z; rr[j+3]=r4.w;
    }
    float sc = 0.f;
    for (int u = 0; u < 32; ++u) {
      float qv = e_b1[u] + e_hw2[u];
      #pragma unroll
      for (int j = 0; j < 32; ++j) qv += rr[j]*e_w1[j*32+u];
      sc += tanh_f(qv)*e_v[u];
    }
    e_sc[t2] = sc;    // bv dropped: constant shift cancels in softmax
  }
  __syncthreads();

  if (tid < 64) {     // softmax over T (wave 0)
    float sv[8]; float m = -1e30f;
    #pragma unroll
    for (int k = 0; k < 8; ++k) { sv[k] = e_sc[tid + 64*k]; m = fmaxf(m, sv[k]); }
    #pragma unroll
    for (int off = 32; off > 0; off >>= 1) m = fmaxf(m, __shfl_xor(m, off));
    float ss = 0.f;
    #pragma unroll
    for (int k = 0; k < 8; ++k) { sv[k] = __expf(sv[k]-m); ss += sv[k]; }
    #pragma unroll
    for (int off = 32; off > 0; off >>= 1) ss += __shfl_xor(ss, off);
    const float inv = 1.f/ss;
    #pragma unroll
    for (int k = 0; k < 8; ++k) e_sc[tid + 64*k] = sv[k]*inv;
  }
  __syncthreads();

  {                   // ctx partial sums (coalesced over u)
    const int u = tid & 31, ch = tid >> 5;
    float acc = 0.f;
    const float* orow = obuf + ((size_t)b*TLEN + ch*64)*32 + u;
    #pragma unroll 4
    for (int t2 = 0; t2 < 64; ++t2) acc += e_sc[ch*64+t2]*orow[(size_t)t2*32];
    e_part[ch*32+u] = acc;
  }
  __syncthreads();
  if (tid < 32) {
    float acc = 0.f;
    #pragma unroll
    for (int ch = 0; ch < 8; ++ch) acc += e_part[ch*32+tid];
    e_ctx[tid] = acc;
  }
  __syncthreads();
  if (tid == 0) {
    float l0 = bd[0], l1 = bd[1];
    #pragma unroll
    for (int u = 0; u < 32; ++u) { l0 += e_ctx[u]*wd[u*2]; l1 += e_ctx[u]*wd[u*2+1]; }
    const float mm = fmaxf(l0,l1);
    const float ex0 = __expf(l0-mm), ex1 = __expf(l1-mm);
    out[b*2+0] = ex0/(ex0+ex1);
    out[b*2+1] = ex1/(ex0+ex1);
  }
}

extern "C" void kernel_launch(void* const* d_in, const int* in_sizes, int n_in,
                              void* d_out, int out_size, void* d_ws, size_t ws_size,
                              hipStream_t stream) {
  const float* x   = (const float*)d_in[0];
  const float* emb = (const float*)d_in[1];
  const float* k0  = (const float*)d_in[2];
  const float* r0  = (const float*)d_in[3];
  const float* bi0 = (const float*)d_in[4];
  const float* bh0 = (const float*)d_in[5];
  const float* k1  = (const float*)d_in[6];
  const float* r1  = (const float*)d_in[7];
  const float* bi1 = (const float*)d_in[8];
  const float* bh1 = (const float*)d_in[9];
  const float* k2  = (const float*)d_in[10];
  const float* r2  = (const float*)d_in[11];
  const float* bi2 = (const float*)d_in[12];
  const float* bh2 = (const float*)d_in[13];
  const float* k3  = (const float*)d_in[14];
  const float* r3  = (const float*)d_in[15];
  const float* bi3 = (const float*)d_in[16];
  const float* bh3 = (const float*)d_in[17];
  const float* w1  = (const float*)d_in[18];
  const float* b1  = (const float*)d_in[19];
  const float* w2  = (const float*)d_in[20];
  const float* b2  = (const float*)d_in[21];
  const float* v   = (const float*)d_in[22];
  const float* bv  = (const float*)d_in[23];
  const float* wd  = (const float*)d_in[24];
  const float* bd  = (const float*)d_in[25];

  float* out  = (float*)d_out;
  float* obuf = (float*)d_ws;   // 512*512*32*4 = 33.5 MB

  rnn_pipe<<<dim3(512), dim3(256), 0, stream>>>(
      x, emb, k0, r0, bi0, bh0, k1, r1, bi1, bh1,
      k2, r2, bi2, bh2, k3, r3, bi3, bh3,
      w1, b1, w2, b2, v, bv, wd, bd, out, obuf);
}

// Round 3
// 1155.793 us; speedup vs baseline: 3.3577x; 3.3577x over previous
//
#include <hip/hip_runtime.h>

#define TLEN 512
#define FIN 16

__device__ __forceinline__ float sigm(float x) { return 1.0f / (1.0f + __expf(-x)); }
__device__ __forceinline__ float tanh_f(float x) {
  x = fminf(fmaxf(x, -15.0f), 15.0f);
  float e = __expf(2.0f * x);
  return (e - 1.0f) / (e + 1.0f);
}

// Symmetric pair-finish for GRU: lanes (2g,2g+1) hold (z,r) gate sums; both
// compute the identical update via shfl_xor (no divergence, no barrier).
__device__ __forceinline__ float gru_fin(float own_main, float own_xh, float own_hhp,
                                         int role, float hold) {
  const float oth_main = __shfl_xor(own_main, 1);
  const float xh  = own_xh  + __shfl_xor(own_xh, 1);
  const float hhp = own_hhp + __shfl_xor(own_hhp, 1);
  const float sz = role ? oth_main : own_main;
  const float sr = role ? own_main : oth_main;
  const float z = sigm(sz);
  const float r = sigm(sr);
  const float hh = tanh_f(xh + r * hhp);
  return z * hold + (1.f - z) * hh;
}

// Layer-pipelined GRU stack: TWO batches per block, 4 waves, launch_bounds(256,1)
// (512-VGPR cap -> weight arrays stay in registers; R2's (256,2) caused scratch
// spills: FETCH 25->350MB).
//   w0: L0 units 0-31 (t=i)   + L3 A-partials (k3 . h2, t=i-3)
//   w1: L0 units 32-63 (t=i)  + input prefetch (t=i+2)
//   w2: L1 (t=i-1)
//   w3: L2 (t=i-2)            + L3 B-part + combine/update (t=i-4)
// One __syncthreads per interval. h-states interleaved [unit][batch] so each
// float4 LDS read feeds both batches.
__global__ __launch_bounds__(256, 1)
void rnn_pipe2(const float* __restrict__ x, const float* __restrict__ emb,
               const float* __restrict__ k0, const float* __restrict__ r0,
               const float* __restrict__ bi0, const float* __restrict__ bh0,
               const float* __restrict__ k1, const float* __restrict__ r1,
               const float* __restrict__ bi1, const float* __restrict__ bh1,
               const float* __restrict__ k2, const float* __restrict__ r2,
               const float* __restrict__ bi2, const float* __restrict__ bh2,
               const float* __restrict__ k3, const float* __restrict__ r3,
               const float* __restrict__ bi3, const float* __restrict__ bh3,
               const float* __restrict__ w1, const float* __restrict__ b1,
               const float* __restrict__ w2, const float* __restrict__ b2,
               const float* __restrict__ vv, const float* __restrict__ bv,
               const float* __restrict__ wd, const float* __restrict__ bd,
               float* __restrict__ out, float* __restrict__ obuf)
{
  __shared__ __align__(16) float s_h0[2][64][2];
  __shared__ __align__(16) float s_h1[2][32][2];
  __shared__ __align__(16) float s_h2[2][32][2];
  __shared__ __align__(16) float s_h3[2][32][2];
  __shared__ __align__(16) float s_inp[2][20][2];
  __shared__ __align__(16) float s_emb[2][TLEN][4];
  __shared__ __align__(16) float s_pA[2][64][2];
  __shared__ __align__(16) float s_pAh[2][64][2];
  // epilogue buffers
  __shared__ __align__(16) float e_w1[1024];
  __shared__ __align__(16) float e_sc[1024];
  __shared__ float e_hw2[64], e_b1[32], e_v[32], e_ctx[64];

  const int tid  = threadIdx.x;
  const int wid  = tid >> 6;
  const int lane = tid & 63;
  const int g    = lane >> 1;
  const int role = lane & 1;
  const int bb0  = blockIdx.x * 2;

  float Wa[96], Wb[48], Wc[48];
  float bm = 0.f, bxh = 0.f, bhh = 0.f;
  float cbm = 0.f, cbxh = 0.f, cbhh = 0.f;
  float rxP = 0.f;

  // ---------------- weight loading (registers) ----------------
  if (wid <= 1) {                       // L0: unit u, gate-col cm
    const int u  = wid * 32 + g;
    const int cm = role ? 64 + u : u;
    #pragma unroll
    for (int j = 0; j < 19; ++j) Wa[j] = k0[j*192 + cm];
    Wa[19] = 0.f;
    #pragma unroll
    for (int j = 0; j < 64; ++j) Wa[20+j] = r0[j*192 + cm];
    #pragma unroll
    for (int jj = 0; jj < 10; ++jj) {
      const int row = role*10 + jj;
      Wb[jj] = (row < 19) ? k0[row*192 + 128 + u] : 0.f;
    }
    #pragma unroll
    for (int jj = 0; jj < 32; ++jj) Wb[10+jj] = r0[(role*32+jj)*192 + 128 + u];
    bm  = bi0[cm] + bh0[cm];
    bxh = role ? 0.f : bi0[128+u];
    bhh = role ? bh0[128+u] : 0.f;
  }
  if (wid == 0) {                       // L3 A-part: k3 over h2
    const int cma = role ? 32 + g : g;
    #pragma unroll
    for (int j = 0; j < 32; ++j) Wc[j] = k3[j*96 + cma];
    #pragma unroll
    for (int jj = 0; jj < 16; ++jj) Wc[32+jj] = k3[(role*16+jj)*96 + 64 + g];
  }
  if (wid == 2) {                       // L1
    const int cm = role ? 32 + g : g;
    #pragma unroll
    for (int j = 0; j < 64; ++j) Wa[j] = k1[j*96 + cm];
    #pragma unroll
    for (int j = 0; j < 32; ++j) Wa[64+j] = r1[j*96 + cm];
    #pragma unroll
    for (int jj = 0; jj < 32; ++jj) Wb[jj] = k1[(role*32+jj)*96 + 64 + g];
    #pragma unroll
    for (int jj = 0; jj < 16; ++jj) Wb[32+jj] = r1[(role*16+jj)*96 + 64 + g];
    bm  = bi1[cm] + bh1[cm];
    bxh = role ? 0.f : bi1[64+g];
    bhh = role ? bh1[64+g] : 0.f;
  }
  if (wid == 3) {                       // L2 + L3 B-part/combine
    const int cm = role ? 32 + g : g;
    #pragma unroll
    for (int j = 0; j < 32; ++j) Wa[j] = k2[j*96 + cm];
    #pragma unroll
    for (int j = 0; j < 32; ++j) Wa[32+j] = r2[j*96 + cm];
    #pragma unroll
    for (int jj = 0; jj < 16; ++jj) Wb[jj] = k2[(role*16+jj)*96 + 64 + g];
    #pragma unroll
    for (int jj = 0; jj < 16; ++jj) Wb[16+jj] = r2[(role*16+jj)*96 + 64 + g];
    bm  = bi2[cm] + bh2[cm];
    bxh = role ? 0.f : bi2[64+g];
    bhh = role ? bh2[64+g] : 0.f;
    #pragma unroll
    for (int j = 0; j < 32; ++j) Wc[j] = r3[j*96 + cm];
    #pragma unroll
    for (int jj = 0; jj < 16; ++jj) Wc[32+jj] = r3[(role*16+jj)*96 + 64 + g];
    cbm  = bi3[cm] + bh3[cm];
    cbxh = bi3[64+g];
    cbhh = bh3[64+g];
  }

  // ---------------- state init + embedding pre-gather ----------------
  ((float*)s_h0)[tid] = 0.f;                       // 256 floats
  if (tid < 128) {
    ((float*)s_h1)[tid] = 0.f;
    ((float*)s_h2)[tid] = 0.f;
    ((float*)s_h3)[tid] = 0.f;
  }
  if (tid < 80) ((float*)s_inp)[tid] = 0.f;

  for (int q = tid; q < 2*TLEN; q += 256) {
    const int b2 = q >> 9, t2 = q & 511;
    const int id = (int)x[((size_t)(bb0+b2)*TLEN + t2)*FIN + 1];
    *(float4*)&s_emb[b2][t2][0] = *(const float4*)&emb[id*4];
  }
  if (wid == 1 && lane < 32) {
    const int b2 = lane >> 4, f = lane & 15;
    rxP = x[((size_t)(bb0+b2)*TLEN + 1)*FIN + f];
  }
  __syncthreads();
  if (tid < 32) {                       // stage t=0 into slot 0
    const int b2 = tid >> 4, f = tid & 15;
    const float v = x[((size_t)(bb0+b2)*TLEN + 0)*FIN + f];
    if (f == 0) s_inp[0][0][b2] = v;
    else if (f >= 2) s_inp[0][f-1][b2] = v;
    if (f < 4) s_inp[0][15+f][b2] = s_emb[b2][0][f];
  }

  // ---------------- pipelined recurrence ----------------
  for (int i = 0; i < 516; ++i) {
    __syncthreads();
    const int wp = i & 1;
    const int rp = wp ^ 1;

    if (wid <= 1) {
      if (i < 512) {                                    // ---- L0, t=i
        const int u = wid*32 + g;
        float a0A = bm, a0B = bm, a1A = 0.f, a1B = 0.f;
        #pragma unroll
        for (int j = 0; j < 20; j += 2) {
          const float4 q = *(const float4*)&s_inp[wp][j][0];
          a0A += Wa[j]*q.x;   a0B += Wa[j]*q.y;
          a1A += Wa[j+1]*q.z; a1B += Wa[j+1]*q.w;
        }
        #pragma unroll
        for (int j = 0; j < 64; j += 2) {
          const float4 q = *(const float4*)&s_h0[rp][j][0];
          a0A += Wa[20+j]*q.x; a0B += Wa[20+j]*q.y;
          a1A += Wa[21+j]*q.z; a1B += Wa[21+j]*q.w;
        }
        float xqA = bxh, xqB = bxh;
        #pragma unroll
        for (int jj = 0; jj < 10; ++jj) {
          const float2 d = *(const float2*)&s_inp[wp][role*10+jj][0];
          xqA += Wb[jj]*d.x; xqB += Wb[jj]*d.y;
        }
        float p0A = bhh, p0B = bhh, p1A = 0.f, p1B = 0.f;
        #pragma unroll
        for (int jj = 0; jj < 32; jj += 2) {
          const float4 q = *(const float4*)&s_h0[rp][role*32+jj][0];
          p0A += Wb[10+jj]*q.x; p0B += Wb[10+jj]*q.y;
          p1A += Wb[11+jj]*q.z; p1B += Wb[11+jj]*q.w;
        }
        const float holdA = s_h0[rp][u][0];
        const float holdB = s_h0[rp][u][1];
        const float hnA = gru_fin(a0A+a1A, xqA, p0A+p1A, role, holdA);
        const float hnB = gru_fin(a0B+a1B, xqB, p0B+p1B, role, holdB);
        if (!role) { s_h0[wp][u][0] = hnA; s_h0[wp][u][1] = hnB; }
      }
      if (wid == 0) {
        if (i >= 3 && i <= 514) {                       // ---- L3 A-part, t=i-3
          float q0A=0.f,q0B=0.f,q1A=0.f,q1B=0.f;
          #pragma unroll
          for (int j = 0; j < 32; j += 2) {
            const float4 q = *(const float4*)&s_h2[rp][j][0];
            q0A += Wc[j]*q.x;   q0B += Wc[j]*q.y;
            q1A += Wc[j+1]*q.z; q1B += Wc[j+1]*q.w;
          }
          float phA=0.f, phB=0.f, ph1A=0.f, ph1B=0.f;
          #pragma unroll
          for (int jj = 0; jj < 16; jj += 2) {
            const float4 q = *(const float4*)&s_h2[rp][role*16+jj][0];
            phA  += Wc[32+jj]*q.x; phB  += Wc[32+jj]*q.y;
            ph1A += Wc[33+jj]*q.z; ph1B += Wc[33+jj]*q.w;
          }
          s_pA[wp][lane][0]  = q0A+q1A;  s_pA[wp][lane][1]  = q0B+q1B;
          s_pAh[wp][lane][0] = phA+ph1A; s_pAh[wp][lane][1] = phB+ph1B;
        }
      } else {                                          // ---- w1: prefetch
        if (lane < 32) {
          const int b2 = lane >> 4, f = lane & 15;
          if (i + 1 <= 511) {
            const int slot = (i+1)&1;
            const float v = rxP;
            if (f == 0) s_inp[slot][0][b2] = v;
            else if (f >= 2) s_inp[slot][f-1][b2] = v;
            if (f < 4) s_inp[slot][15+f][b2] = s_emb[b2][i+1][f];
          }
          if (i + 2 <= 511) rxP = x[((size_t)(bb0+b2)*TLEN + (i+2))*FIN + f];
        }
      }
    } else if (wid == 2) {
      if (i >= 1 && i <= 512) {                         // ---- L1, t=i-1
        float a0A = bm, a0B = bm, a1A=0.f, a1B=0.f;
        #pragma unroll
        for (int j = 0; j < 64; j += 2) {
          const float4 q = *(const float4*)&s_h0[rp][j][0];
          a0A += Wa[j]*q.x;   a0B += Wa[j]*q.y;
          a1A += Wa[j+1]*q.z; a1B += Wa[j+1]*q.w;
        }
        #pragma unroll
        for (int j = 0; j < 32; j += 2) {
          const float4 q = *(const float4*)&s_h1[rp][j][0];
          a0A += Wa[64+j]*q.x; a0B += Wa[64+j]*q.y;
          a1A += Wa[65+j]*q.z; a1B += Wa[65+j]*q.w;
        }
        float x0A = bxh, x0B = bxh, x1A = 0.f, x1B = 0.f;
        #pragma unroll
        for (int jj = 0; jj < 32; jj += 2) {
          const float4 q = *(const float4*)&s_h0[rp][role*32+jj][0];
          x0A += Wb[jj]*q.x;   x0B += Wb[jj]*q.y;
          x1A += Wb[jj+1]*q.z; x1B += Wb[jj+1]*q.w;
        }
        float p0A = bhh, p0B = bhh, p1A = 0.f, p1B = 0.f;
        #pragma unroll
        for (int jj = 0; jj < 16; jj += 2) {
          const float4 q = *(const float4*)&s_h1[rp][role*16+jj][0];
          p0A += Wb[32+jj]*q.x; p0B += Wb[32+jj]*q.y;
          p1A += Wb[33+jj]*q.z; p1B += Wb[33+jj]*q.w;
        }
        const float holdA = s_h1[rp][g][0];
        const float holdB = s_h1[rp][g][1];
        const float hnA = gru_fin(a0A+a1A, x0A+x1A, p0A+p1A, role, holdA);
        const float hnB = gru_fin(a0B+a1B, x0B+x1B, p0B+p1B, role, holdB);
        if (!role) { s_h1[wp][g][0] = hnA; s_h1[wp][g][1] = hnB; }
      }
    } else {
      if (i >= 2 && i <= 513) {                         // ---- L2, t=i-2
        float a0A = bm, a0B = bm, a1A=0.f, a1B=0.f;
        #pragma unroll
        for (int j = 0; j < 32; j += 2) {
          const float4 q = *(const float4*)&s_h1[rp][j][0];
          a0A += Wa[j]*q.x;   a0B += Wa[j]*q.y;
          a1A += Wa[j+1]*q.z; a1B += Wa[j+1]*q.w;
        }
        #pragma unroll
        for (int j = 0; j < 32; j += 2) {
          const float4 q = *(const float4*)&s_h2[rp][j][0];
          a0A += Wa[32+j]*q.x; a0B += Wa[32+j]*q.y;
          a1A += Wa[33+j]*q.z; a1B += Wa[33+j]*q.w;
        }
        float x0A = bxh, x0B = bxh, x1A = 0.f, x1B = 0.f;
        #pragma unroll
        for (int jj = 0; jj < 16; jj += 2) {
          const float4 q = *(const float4*)&s_h1[rp][role*16+jj][0];
          x0A += Wb[jj]*q.x;   x0B += Wb[jj]*q.y;
          x1A += Wb[jj+1]*q.z; x1B += Wb[jj+1]*q.w;
        }
        float p0A = bhh, p0B = bhh, p1A = 0.f, p1B = 0.f;
        #pragma unroll
        for (int jj = 0; jj < 16; jj += 2) {
          const float4 q = *(const float4*)&s_h2[rp][role*16+jj][0];
          p0A += Wb[16+jj]*q.x; p0B += Wb[16+jj]*q.y;
          p1A += Wb[17+jj]*q.z; p1B += Wb[17+jj]*q.w;
        }
        const float holdA = s_h2[rp][g][0];
        const float holdB = s_h2[rp][g][1];
        const float hnA = gru_fin(a0A+a1A, x0A+x1A, p0A+p1A, role, holdA);
        const float hnB = gru_fin(a0B+a1B, x0B+x1B, p0B+p1B, role, holdB);
        if (!role) { s_h2[wp][g][0] = hnA; s_h2[wp][g][1] = hnB; }
      }
      if (i >= 4) {                                     // ---- L3 B + combine, t=i-4
        float q0A=0.f,q0B=0.f,q1A=0.f,q1B=0.f;
        #pragma unroll
        for (int jj = 0; jj < 32; jj += 2) {
          const float4 q = *(const float4*)&s_h3[rp][jj][0];
          q0A += Wc[jj]*q.x;   q0B += Wc[jj]*q.y;
          q1A += Wc[jj+1]*q.z; q1B += Wc[jj+1]*q.w;
        }
        float ph0A=0.f, ph0B=0.f, ph1A=0.f, ph1B=0.f;
        #pragma unroll
        for (int jj = 0; jj < 16; jj += 2) {
          const float4 q = *(const float4*)&s_h3[rp][role*16+jj][0];
          ph0A += Wc[32+jj]*q.x; ph0B += Wc[32+jj]*q.y;
          ph1A += Wc[33+jj]*q.z; ph1B += Wc[33+jj]*q.w;
        }
        const float mainA = s_pA[rp][lane][0] + q0A + q1A + cbm;
        const float mainB = s_pA[rp][lane][1] + q0B + q1B + cbm;
        const float xhA_own = s_pAh[rp][lane][0];
        const float xhB_own = s_pAh[rp][lane][1];
        const float phA_own = ph0A + ph1A;
        const float phB_own = ph0B + ph1B;

        const float othA = __shfl_xor(mainA, 1);
        const float othB = __shfl_xor(mainB, 1);
        const float xhA = xhA_own + __shfl_xor(xhA_own, 1) + cbxh;
        const float xhB = xhB_own + __shfl_xor(xhB_own, 1) + cbxh;
        const float hhpA = phA_own + __shfl_xor(phA_own, 1) + cbhh;
        const float hhpB = phB_own + __shfl_xor(phB_own, 1) + cbhh;

        const float szA = role ? othA : mainA;
        const float srA = role ? mainA : othA;
        const float szB = role ? othB : mainB;
        const float srB = role ? mainB : othB;
        const float zA = sigm(szA), rA = sigm(srA);
        const float zB = sigm(szB), rB = sigm(srB);
        const float hhA = tanh_f(xhA + rA*hhpA);
        const float hhB = tanh_f(xhB + rB*hhpB);
        const float hnA = zA*s_h3[rp][g][0] + (1.f-zA)*hhA;
        const float hnB = zB*s_h3[rp][g][1] + (1.f-zB)*hhB;
        if (!role) {
          s_h3[wp][g][0] = hnA;
          s_h3[wp][g][1] = hnB;
          obuf[((size_t)(bb0+0)*TLEN + (i-4))*32 + g] = hnA;
          obuf[((size_t)(bb0+1)*TLEN + (i-4))*32 + g] = hnB;
        }
      }
    }
  }
  __syncthreads();

  // ---------------- attention epilogue (hT = s_h3[1]) ----------------
  for (int kk = tid; kk < 1024; kk += 256) e_w1[kk] = w1[kk];
  if (tid < 32) { e_b1[tid] = b1[tid]; e_v[tid] = vv[tid]; }
  if (tid >= 64 && tid < 128) {
    const int u = tid & 31, bb = (tid - 64) >> 5;
    float s = b2[u];
    #pragma unroll
    for (int j = 0; j < 32; ++j) s += s_h3[1][j][bb] * w2[j*32 + u];
    e_hw2[bb*32 + u] = s;
  }
  __syncthreads();

  #pragma unroll
  for (int c = 0; c < 4; ++c) {   // scores: 1024 tasks (2 batches x 512 t)
    const int idx = c*256 + tid;
    const int bb = idx >> 9, t2 = idx & 511;
    const float* row = obuf + ((size_t)(bb0+bb)*TLEN + t2)*32;
    float rr[32];
    #pragma unroll
    for (int j = 0; j < 32; j += 4) {
      const float4 r4 = *(const float4*)&row[j];
      rr[j]=r4.x; rr[j+1]=r4.y; rr[j+2]=r4.z; rr[j+3]=r4.w;
    }
    float sc = 0.f;
    for (int u = 0; u < 32; ++u) {
      float qv = e_b1[u] + e_hw2[bb*32 + u];
      #pragma unroll
      for (int j = 0; j < 32; ++j) qv += rr[j]*e_w1[j*32+u];
      sc += tanh_f(qv)*e_v[u];
    }
    e_sc[idx] = sc;    // bv dropped: constant shift cancels in softmax
  }
  __syncthreads();

  {  // softmax over T per batch: wave 0 -> b=0, wave 1 -> b=1
    if (wid < 2) {
      const int bb = wid;
      float sv[8]; float m = -1e30f;
      #pragma unroll
      for (int k = 0; k < 8; ++k) { sv[k] = e_sc[bb*512 + lane + 64*k]; m = fmaxf(m, sv[k]); }
      #pragma unroll
      for (int off = 32; off > 0; off >>= 1) m = fmaxf(m, __shfl_xor(m, off));
      float ss = 0.f;
      #pragma unroll
      for (int k = 0; k < 8; ++k) { sv[k] = __expf(sv[k]-m); ss += sv[k]; }
      #pragma unroll
      for (int off = 32; off > 0; off >>= 1) ss += __shfl_xor(ss, off);
      const float inv = 1.f/ss;
      #pragma unroll
      for (int k = 0; k < 8; ++k) e_sc[bb*512 + lane + 64*k] = sv[k]*inv;
    }
  }
  __syncthreads();

  if (tid < 64) {     // ctx = sum_t p_t * out_t (coalesced across u)
    const int u = tid & 31, bb = tid >> 5;
    float acc = 0.f;
    const float* orow = obuf + (size_t)(bb0+bb)*TLEN*32 + u;
    const float* prow = e_sc + bb*512;
    #pragma unroll 4
    for (int t2 = 0; t2 < 512; ++t2) acc += prow[t2]*orow[(size_t)t2*32];
    e_ctx[bb*32 + u] = acc;
  }
  __syncthreads();

  if (tid < 2) {      // final 2-class softmax
    const int bb = tid;
    float l0 = bd[0], l1 = bd[1];
    #pragma unroll
    for (int u = 0; u < 32; ++u) {
      const float cv = e_ctx[bb*32 + u];
      l0 += cv*wd[u*2]; l1 += cv*wd[u*2+1];
    }
    const float mm = fmaxf(l0, l1);
    const float ex0 = __expf(l0-mm), ex1 = __expf(l1-mm);
    const float den = ex0 + ex1;
    out[(bb0+bb)*2 + 0] = ex0/den;
    out[(bb0+bb)*2 + 1] = ex1/den;
  }
}

extern "C" void kernel_launch(void* const* d_in, const int* in_sizes, int n_in,
                              void* d_out, int out_size, void* d_ws, size_t ws_size,
                              hipStream_t stream) {
  const float* x   = (const float*)d_in[0];
  const float* emb = (const float*)d_in[1];
  const float* k0  = (const float*)d_in[2];
  const float* r0  = (const float*)d_in[3];
  const float* bi0 = (const float*)d_in[4];
  const float* bh0 = (const float*)d_in[5];
  const float* k1  = (const float*)d_in[6];
  const float* r1  = (const float*)d_in[7];
  const float* bi1 = (const float*)d_in[8];
  const float* bh1 = (const float*)d_in[9];
  const float* k2  = (const float*)d_in[10];
  const float* r2  = (const float*)d_in[11];
  const float* bi2 = (const float*)d_in[12];
  const float* bh2 = (const float*)d_in[13];
  const float* k3  = (const float*)d_in[14];
  const float* r3  = (const float*)d_in[15];
  const float* bi3 = (const float*)d_in[16];
  const float* bh3 = (const float*)d_in[17];
  const float* w1  = (const float*)d_in[18];
  const float* b1  = (const float*)d_in[19];
  const float* w2  = (const float*)d_in[20];
  const float* b2  = (const float*)d_in[21];
  const float* v   = (const float*)d_in[22];
  const float* bv  = (const float*)d_in[23];
  const float* wd  = (const float*)d_in[24];
  const float* bd  = (const float*)d_in[25];

  float* out  = (float*)d_out;
  float* obuf = (float*)d_ws;   // 512*512*32*4 = 33.5 MB

  rnn_pipe2<<<dim3(256), dim3(256), 0, stream>>>(
      x, emb, k0, r0, bi0, bh0, k1, r1, bi1, bh1,
      k2, r2, bi2, bh2, k3, r3, bi3, bh3,
      w1, b1, w2, b2, v, bv, wd, bd, out, obuf);
}